// Round 1
// baseline (317.214 us; speedup 1.0000x reference)
//
#include <hip/hip_runtime.h>

#define DMODEL 1024
#define NHEADS 16
#define HDIM   64
#define BATCH  2
#define SEQ    2048
#define MROWS  (BATCH*SEQ)

typedef __bf16 bf16x8 __attribute__((ext_vector_type(8)));
typedef float floatx4 __attribute__((ext_vector_type(4)));

typedef const __attribute__((address_space(1))) void gvoid;
typedef __attribute__((address_space(3))) void lvoid;

__device__ inline unsigned short f2bf(float f) {
  unsigned int u = __float_as_uint(f);
  u += 0x7fffu + ((u >> 16) & 1u);
  return (unsigned short)(u >> 16);
}

__global__ void cast_f32_bf16(const float* __restrict__ in,
                              unsigned short* __restrict__ out, int n4) {
  int i = blockIdx.x * blockDim.x + threadIdx.x;
  if (i < n4) {
    float4 f = ((const float4*)in)[i];
    ushort4 o;
    o.x = f2bf(f.x); o.y = f2bf(f.y); o.z = f2bf(f.z); o.w = f2bf(f.w);
    ((ushort4*)out)[i] = o;
  }
}

// NT GEMM: C[m][n] = sum_k A[m][k]*Bw[n][k] + bias[n]
// MODE 0: write bf16 to [b][h][s][d] layout (qkv). MODE 1: write fp32 row-major.
template<int MODE>
__global__ __launch_bounds__(256)
void gemm_nt(const unsigned short* __restrict__ A,
             const unsigned short* __restrict__ Bw,
             const float* __restrict__ bias,
             unsigned short* __restrict__ outb,
             float* __restrict__ outf,
             int K)
{
  __shared__ unsigned short As[128*32];
  __shared__ unsigned short Bs[128*32];
  const int tid  = threadIdx.x;
  const int wid  = tid >> 6;
  const int lane = tid & 63;
  const int brow = blockIdx.y * 128;
  const int bcol = blockIdx.x * 128;
  const int wr = (wid >> 1) * 64;
  const int wc = (wid & 1) * 64;

  floatx4 acc[4][4] = {};

  const int sr = wid*16 + (lane >> 2);   // staging row within 64-row half
  const int sc = (lane & 3) * 8;         // staging k-offset (elements)
  const int fr = lane & 15;
  const int fk = (lane >> 4) * 8;

  for (int kt = 0; kt < K; kt += 32) {
    __syncthreads();
#pragma unroll
    for (int i = 0; i < 2; ++i) {
      __builtin_amdgcn_global_load_lds(
          (gvoid*)(A + (size_t)(brow + i*64 + sr)*K + kt + sc),
          (lvoid*)(As + i*2048 + wid*512), 16, 0, 0);
      __builtin_amdgcn_global_load_lds(
          (gvoid*)(Bw + (size_t)(bcol + i*64 + sr)*K + kt + sc),
          (lvoid*)(Bs + i*2048 + wid*512), 16, 0, 0);
    }
    __syncthreads();
    bf16x8 af[4], bfv[4];
#pragma unroll
    for (int m = 0; m < 4; ++m)
      af[m] = *(const bf16x8*)(As + (wr + m*16 + fr)*32 + fk);
#pragma unroll
    for (int n = 0; n < 4; ++n)
      bfv[n] = *(const bf16x8*)(Bs + (wc + n*16 + fr)*32 + fk);
#pragma unroll
    for (int m = 0; m < 4; ++m)
#pragma unroll
      for (int n = 0; n < 4; ++n)
        acc[m][n] = __builtin_amdgcn_mfma_f32_16x16x32_bf16(af[m], bfv[n], acc[m][n], 0, 0, 0);
  }

  const int er = (lane >> 4) * 4;
  const int ec = lane & 15;
#pragma unroll
  for (int m = 0; m < 4; ++m) {
#pragma unroll
    for (int n = 0; n < 4; ++n) {
      const int col = bcol + wc + n*16 + ec;
      const float bv = bias[col];
#pragma unroll
      for (int j = 0; j < 4; ++j) {
        const int row = brow + wr + m*16 + er + j;
        const float val = acc[m][n][j] + bv;
        if (MODE == 0) {
          const int bi = row >> 11, s = row & 2047;
          const int h = col >> 6, d = col & 63;
          outb[(((size_t)(bi*NHEADS + h)*SEQ + s) << 6) + d] = f2bf(val);
        } else {
          outf[(size_t)row*DMODEL + col] = val;
        }
      }
    }
  }
}

// Flash attention: grid (qtile=32, head=16, batch=2), 256 threads = 4 waves.
// Each wave owns 16 q-rows. 32-key steps, swapped QK^T so softmax is lane-local.
__global__ __launch_bounds__(256)
void attn_fwd(const unsigned short* __restrict__ qb,
              const unsigned short* __restrict__ kb,
              const unsigned short* __restrict__ vb,
              const int* __restrict__ ids,
              unsigned short* __restrict__ outb)
{
  const int qt = blockIdx.x, h = blockIdx.y, bi = blockIdx.z;
  const int tid = threadIdx.x, wid = tid >> 6, lane = tid & 63;
  const int qbase = qt * 64;
  const size_t hoff = (size_t)(bi*NHEADS + h) * SEQ * HDIM;
  const unsigned short* Qh = qb + hoff;
  const unsigned short* Kh = kb + hoff;
  const unsigned short* Vh = vb + hoff;

  __shared__ unsigned short Ks[32*64];       // swizzled row-major [32][64]
  __shared__ unsigned short Vt[64*40];       // transposed, padded rows (40)
  __shared__ unsigned short Ps[4][16*32];    // per-wave P tile
  __shared__ unsigned char padm[SEQ];

  for (int i = tid; i < SEQ; i += 256) padm[i] = (ids[bi*SEQ + i] == 0) ? 1 : 0;

  const int qg = qbase + wid*16 + (lane & 15);
  bf16x8 qf[2];
#pragma unroll
  for (int c = 0; c < 2; ++c)
    qf[c] = *(const bf16x8*)(Qh + (size_t)qg*HDIM + c*32 + (lane >> 4)*8);

  float m_run = -INFINITY, l_run = 0.f;
  floatx4 Oacc[4] = {};

  const int nsteps = (qbase + 64) >> 5;
  const int srow = tid >> 3;   // 0..31
  const int schk = tid & 7;    // 0..7

  for (int kbv = 0; kbv < nsteps; ++kbv) {
    const int kb0 = kbv * 32;
    __syncthreads();
    {
      bf16x8 kv = *(const bf16x8*)(Kh + (size_t)(kb0 + srow)*HDIM + schk*8);
      *(bf16x8*)((char*)Ks + srow*128 + ((schk ^ (srow & 7)) * 16)) = kv;
      bf16x8 vv = *(const bf16x8*)(Vh + (size_t)(kb0 + srow)*HDIM + schk*8);
#pragma unroll
      for (int j = 0; j < 8; ++j)
        Vt[(schk*8 + j)*40 + srow] = ((const unsigned short*)&vv)[j];
    }
    __syncthreads();

    floatx4 st[2] = {};
#pragma unroll
    for (int t = 0; t < 2; ++t) {
      const int krow = t*16 + (lane & 15);
#pragma unroll
      for (int c = 0; c < 2; ++c) {
        const int ch = (c*4 + (lane >> 4)) ^ (krow & 7);
        bf16x8 kf = *(const bf16x8*)((char*)Ks + krow*128 + ch*16);
        st[t] = __builtin_amdgcn_mfma_f32_16x16x32_bf16(kf, qf[c], st[t], 0, 0, 0);
      }
    }

    float vals[8];
    float tmax = -INFINITY;
#pragma unroll
    for (int t = 0; t < 2; ++t)
#pragma unroll
      for (int r = 0; r < 4; ++r) {
        const int kg = kb0 + t*16 + (lane >> 4)*4 + r;
        float s = st[t][r];
        s = (kg <= qg && !padm[kg]) ? s * 0.125f : -1e9f;
        vals[t*4 + r] = s;
        tmax = fmaxf(tmax, s);
      }
    tmax = fmaxf(tmax, __shfl_xor(tmax, 16));
    tmax = fmaxf(tmax, __shfl_xor(tmax, 32));
    const float mnew = fmaxf(m_run, tmax);
    const float alpha = expf(m_run - mnew);
    float psum = 0.f;
    unsigned short pb[8];
#pragma unroll
    for (int i = 0; i < 8; ++i) {
      const float p = expf(vals[i] - mnew);
      psum += p;
      pb[i] = f2bf(p);
    }
    psum += __shfl_xor(psum, 16);
    psum += __shfl_xor(psum, 32);
    l_run = l_run * alpha + psum;
    m_run = mnew;

    unsigned short* Pw = Ps[wid];
    {
      ushort4 p0 = make_ushort4(pb[0], pb[1], pb[2], pb[3]);
      ushort4 p1 = make_ushort4(pb[4], pb[5], pb[6], pb[7]);
      *(ushort4*)(Pw + (lane & 15)*32 + (lane >> 4)*4)      = p0;
      *(ushort4*)(Pw + (lane & 15)*32 + 16 + (lane >> 4)*4) = p1;
    }

#pragma unroll
    for (int r = 0; r < 4; ++r) {
      const float ar = __shfl(alpha, (lane >> 4)*4 + r);
#pragma unroll
      for (int n = 0; n < 4; ++n) Oacc[n][r] *= ar;
    }

    bf16x8 pf = *(const bf16x8*)(Pw + (lane & 15)*32 + (lane >> 4)*8);
#pragma unroll
    for (int n = 0; n < 4; ++n) {
      bf16x8 vf = *(const bf16x8*)(Vt + (n*16 + (lane & 15))*40 + (lane >> 4)*8);
      Oacc[n] = __builtin_amdgcn_mfma_f32_16x16x32_bf16(pf, vf, Oacc[n], 0, 0, 0);
    }
  }

#pragma unroll
  for (int r = 0; r < 4; ++r) {
    const float lr = __shfl(l_run, (lane >> 4)*4 + r);
    const float inv = 1.f / lr;
    const int srowg = qbase + wid*16 + (lane >> 4)*4 + r;
#pragma unroll
    for (int n = 0; n < 4; ++n) {
      const float val = Oacc[n][r] * inv;
      const int col = h*HDIM + n*16 + (lane & 15);
      outb[(size_t)(bi*SEQ + srowg)*DMODEL + col] = f2bf(val);
    }
  }
}

extern "C" void kernel_launch(void* const* d_in, const int* in_sizes, int n_in,
                              void* d_out, int out_size, void* d_ws, size_t ws_size,
                              hipStream_t stream)
{
  const float* x  = (const float*)d_in[0];
  const int*   ids= (const int*)d_in[1];
  const float* Wq = (const float*)d_in[2];
  const float* bq = (const float*)d_in[3];
  const float* Wk = (const float*)d_in[4];
  const float* bk = (const float*)d_in[5];
  const float* Wv = (const float*)d_in[6];
  const float* bv = (const float*)d_in[7];
  const float* Wo = (const float*)d_in[8];
  const float* bo = (const float*)d_in[9];
  float* out = (float*)d_out;

  char* ws = (char*)d_ws;
  unsigned short* xb   = (unsigned short*)(ws);
  unsigned short* wqb  = (unsigned short*)(ws + ( 8u<<20));
  unsigned short* wkb  = (unsigned short*)(ws + (10u<<20));
  unsigned short* wvb  = (unsigned short*)(ws + (12u<<20));
  unsigned short* wob  = (unsigned short*)(ws + (14u<<20));
  unsigned short* qbuf = (unsigned short*)(ws + (16u<<20));
  unsigned short* kbuf = (unsigned short*)(ws + (24u<<20));
  unsigned short* vbuf = (unsigned short*)(ws + (32u<<20));
  unsigned short* abuf = (unsigned short*)(ws + (40u<<20));

  cast_f32_bf16<<<4096, 256, 0, stream>>>(x,  xb,  MROWS*DMODEL/4);
  cast_f32_bf16<<<1024, 256, 0, stream>>>(Wq, wqb, DMODEL*DMODEL/4);
  cast_f32_bf16<<<1024, 256, 0, stream>>>(Wk, wkb, DMODEL*DMODEL/4);
  cast_f32_bf16<<<1024, 256, 0, stream>>>(Wv, wvb, DMODEL*DMODEL/4);
  cast_f32_bf16<<<1024, 256, 0, stream>>>(Wo, wob, DMODEL*DMODEL/4);

  dim3 gg(DMODEL/128, MROWS/128);
  gemm_nt<0><<<gg, 256, 0, stream>>>(xb, wqb, bq, qbuf, nullptr, DMODEL);
  gemm_nt<0><<<gg, 256, 0, stream>>>(xb, wkb, bk, kbuf, nullptr, DMODEL);
  gemm_nt<0><<<gg, 256, 0, stream>>>(xb, wvb, bv, vbuf, nullptr, DMODEL);

  attn_fwd<<<dim3(SEQ/64, NHEADS, BATCH), 256, 0, stream>>>(qbuf, kbuf, vbuf, ids, abuf);

  gemm_nt<1><<<gg, 256, 0, stream>>>(abuf, wob, bo, nullptr, out, DMODEL);
}

// Round 2
// 186.742 us; speedup vs baseline: 1.6987x; 1.6987x over previous
//
#include <hip/hip_runtime.h>

#define DMODEL 1024
#define NHEADS 16
#define HDIM   64
#define BATCH  2
#define SEQ    2048
#define MROWS  (BATCH*SEQ)

typedef __bf16 bf16x8 __attribute__((ext_vector_type(8)));
typedef float floatx4 __attribute__((ext_vector_type(4)));

typedef const __attribute__((address_space(1))) void gvoid;
typedef __attribute__((address_space(3))) void lvoid;

__device__ inline unsigned short f2bf(float f) {
  unsigned int u = __float_as_uint(f);
  u += 0x7fffu + ((u >> 16) & 1u);
  return (unsigned short)(u >> 16);
}

__global__ void cast_f32_bf16(const float* __restrict__ in,
                              unsigned short* __restrict__ out, int n4) {
  int i = blockIdx.x * blockDim.x + threadIdx.x;
  if (i < n4) {
    float4 f = ((const float4*)in)[i];
    ((ushort4*)out)[i] = make_ushort4(f2bf(f.x), f2bf(f.y), f2bf(f.z), f2bf(f.w));
  }
}

__global__ void cast_w4(const float* __restrict__ a, const float* __restrict__ b,
                        const float* __restrict__ c, const float* __restrict__ d,
                        unsigned short* __restrict__ oa, unsigned short* __restrict__ ob,
                        unsigned short* __restrict__ oc, unsigned short* __restrict__ od) {
  const int i = blockIdx.x * blockDim.x + threadIdx.x;
  const float* s = blockIdx.y == 0 ? a : blockIdx.y == 1 ? b : blockIdx.y == 2 ? c : d;
  unsigned short* o = blockIdx.y == 0 ? oa : blockIdx.y == 1 ? ob : blockIdx.y == 2 ? oc : od;
  float4 f = ((const float4*)s)[i];
  ((ushort4*)o)[i] = make_ushort4(f2bf(f.x), f2bf(f.y), f2bf(f.z), f2bf(f.w));
}

// NT GEMM: C[m][n] = sum_k A[m][k]*W[n][k] + bias[n]
// MODE 0: fused QKV (N=3072, block col selects W/bias); q,k -> [b,h,s,d] bf16,
//         v -> [b,h,d,s] bf16 (pre-transposed for attention's PV B-fragment).
// MODE 1: fp32 row-major out (output projection).
template<int MODE>
__global__ __launch_bounds__(256)
void gemm_nt(const unsigned short* __restrict__ A,
             const unsigned short* __restrict__ W0,
             const unsigned short* __restrict__ W1,
             const unsigned short* __restrict__ W2,
             const float* __restrict__ b0,
             const float* __restrict__ b1,
             const float* __restrict__ b2,
             unsigned short* __restrict__ qout,
             unsigned short* __restrict__ kout,
             unsigned short* __restrict__ vout,
             float* __restrict__ outf)
{
  const int K = DMODEL;
  __shared__ unsigned short As[128*32];
  __shared__ unsigned short Bs[128*32];
  const int tid  = threadIdx.x;
  const int wid  = tid >> 6;
  const int lane = tid & 63;
  const int brow = blockIdx.y * 128;
  const int bcol = blockIdx.x * 128;
  const int wr = (wid >> 1) * 64;
  const int wc = (wid & 1) * 64;

  int which = 0;
  const unsigned short* Bw = W0;
  const float* bias = b0;
  int bcolL = bcol;
  if (MODE == 0) {
    which = bcol >> 10;
    Bw   = which == 0 ? W0 : which == 1 ? W1 : W2;
    bias = which == 0 ? b0 : which == 1 ? b1 : b2;
    bcolL = bcol & 1023;
  }

  floatx4 acc[4][4] = {};

  const int sr = wid*16 + (lane >> 2);
  const int sc = (lane & 3) * 8;
  const int fr = lane & 15;
  const int fk = (lane >> 4) * 8;

  for (int kt = 0; kt < K; kt += 32) {
    __syncthreads();
#pragma unroll
    for (int i = 0; i < 2; ++i) {
      __builtin_amdgcn_global_load_lds(
          (gvoid*)(A + (size_t)(brow + i*64 + sr)*K + kt + sc),
          (lvoid*)(As + i*2048 + wid*512), 16, 0, 0);
      __builtin_amdgcn_global_load_lds(
          (gvoid*)(Bw + (size_t)(bcolL + i*64 + sr)*K + kt + sc),
          (lvoid*)(Bs + i*2048 + wid*512), 16, 0, 0);
    }
    __syncthreads();
    bf16x8 af[4], bfv[4];
#pragma unroll
    for (int m = 0; m < 4; ++m)
      af[m] = *(const bf16x8*)(As + (wr + m*16 + fr)*32 + fk);
#pragma unroll
    for (int n = 0; n < 4; ++n)
      bfv[n] = *(const bf16x8*)(Bs + (wc + n*16 + fr)*32 + fk);
#pragma unroll
    for (int m = 0; m < 4; ++m)
#pragma unroll
      for (int n = 0; n < 4; ++n)
        acc[m][n] = __builtin_amdgcn_mfma_f32_16x16x32_bf16(af[m], bfv[n], acc[m][n], 0, 0, 0);
  }

  const int er = (lane >> 4) * 4;
  const int ec = lane & 15;
#pragma unroll
  for (int m = 0; m < 4; ++m) {
#pragma unroll
    for (int n = 0; n < 4; ++n) {
      const int colL = bcolL + wc + n*16 + ec;
      const float bv = bias[colL];
#pragma unroll
      for (int j = 0; j < 4; ++j) {
        const int row = brow + wr + m*16 + er + j;
        const float val = acc[m][n][j] + bv;
        if (MODE == 0) {
          const int bi = row >> 11, s = row & 2047;
          const int hh = colL >> 6, dd = colL & 63;
          if (which == 2)
            vout[((size_t)(bi*NHEADS + hh)*HDIM + dd)*SEQ + s] = f2bf(val);
          else {
            unsigned short* o = (which == 0) ? qout : kout;
            o[((size_t)(bi*NHEADS + hh)*SEQ + s)*HDIM + dd] = f2bf(val);
          }
        } else {
          outf[(size_t)row*DMODEL + bcol + wc + n*16 + ec] = val;
        }
      }
    }
  }
}

// Flash attention. grid (qtile=32, head=16, batch=2), 256 thr = 4 waves,
// wave owns 16 q-rows, KVBLK=64. K [64k][64d] and V^T [64d][64k] staged via
// global_load_lds with pre-swizzled source (chunk ^= row&7); swapped QK^T so
// softmax state is lane-local per q-row. exp2-domain softmax. Pad mask as
// bit-words with a no-pad fast path.
__global__ __launch_bounds__(256)
void attn_fwd(const unsigned short* __restrict__ qb,
              const unsigned short* __restrict__ kb,
              const unsigned short* __restrict__ vtb,
              const int* __restrict__ ids,
              unsigned short* __restrict__ outb)
{
  const int qt = blockIdx.x, h = blockIdx.y, bi = blockIdx.z;
  const int tid = threadIdx.x, wid = tid >> 6, lane = tid & 63;
  const int qbase = qt * 64;
  const size_t hoff = (size_t)(bi*NHEADS + h) * SEQ * HDIM;
  const unsigned short* Qh  = qb  + hoff;
  const unsigned short* Kh  = kb  + hoff;
  const unsigned short* Vth = vtb + hoff;   // [d][s]

  __shared__ unsigned short Ks[64*64];      // [k][d], chunk-swizzled
  __shared__ unsigned short Vs[64*64];      // [d][k], chunk-swizzled
  __shared__ unsigned short Ps[4][16*64];   // per-wave P, chunk-swizzled
  __shared__ unsigned int   padw[SEQ/32];

  // pad bitmask, one bit per key
  for (int it = 0; it < SEQ/256; ++it) {
    const int key = it*256 + tid;
    const unsigned long long m = __ballot(ids[bi*SEQ + key] == 0);
    if (lane == 0) {
      const int base = (it*256 + wid*64) >> 5;
      padw[base]   = (unsigned int)m;
      padw[base+1] = (unsigned int)(m >> 32);
    }
  }

  const int q_   = lane & 15;
  const int hi4  = lane >> 4;        // 0..3
  const int koff = hi4 * 4;
  const int qg = qbase + wid*16 + q_;
  bf16x8 qf[2];
#pragma unroll
  for (int c = 0; c < 2; ++c)
    qf[c] = *(const bf16x8*)(Qh + (size_t)qg*HDIM + c*32 + hi4*8);

  const float SC2 = 0.125f * 1.44269504088896f;
  float m2 = -INFINITY, l_run = 0.f;
  floatx4 Oacc[4] = {};

  // staging geometry: 512 chunks of 16B; thread covers chunks tid and tid+256
  const int r0 = tid >> 3;
  const int sw = ((tid & 7) ^ (r0 & 7)) * 8;   // (r0+32)&7 == r0&7

  for (int kbv = 0; kbv <= qt; ++kbv) {
    const int kb0 = kbv * 64;
    __syncthreads();
    {
      const unsigned short* kbase = Kh + (size_t)kb0 * HDIM;
      const unsigned short* vbase = Vth + kb0;
      __builtin_amdgcn_global_load_lds((gvoid*)(kbase + r0*64 + sw),
                                       (lvoid*)(Ks + tid*8), 16, 0, 0);
      __builtin_amdgcn_global_load_lds((gvoid*)(kbase + (r0+32)*64 + sw),
                                       (lvoid*)(Ks + (tid+256)*8), 16, 0, 0);
      __builtin_amdgcn_global_load_lds((gvoid*)(vbase + (size_t)r0*SEQ + sw),
                                       (lvoid*)(Vs + tid*8), 16, 0, 0);
      __builtin_amdgcn_global_load_lds((gvoid*)(vbase + (size_t)(r0+32)*SEQ + sw),
                                       (lvoid*)(Vs + (tid+256)*8), 16, 0, 0);
    }
    __syncthreads();

    // QK^T (swapped): st[t] = S^T tile, row = key t*16+koff+r, col = q_
    floatx4 st[4] = {};
#pragma unroll
    for (int t = 0; t < 4; ++t) {
      const int kr = t*16 + q_;
#pragma unroll
      for (int c = 0; c < 2; ++c) {
        const int cd = ((c*4 + hi4) ^ (kr & 7)) * 8;
        bf16x8 kf = *(const bf16x8*)(Ks + kr*64 + cd);
        st[t] = __builtin_amdgcn_mfma_f32_16x16x32_bf16(kf, qf[c], st[t], 0, 0, 0);
      }
    }

    const int kw = kb0 >> 5;
    const unsigned int w0 = padw[kw], w1 = padw[kw+1];
    float vals[16];
    if (((w0 | w1) == 0u) && (kbv != qt)) {
#pragma unroll
      for (int t = 0; t < 4; ++t)
#pragma unroll
        for (int r = 0; r < 4; ++r) vals[t*4+r] = st[t][r];
    } else {
      const unsigned long long wm = (unsigned long long)w0 | ((unsigned long long)w1 << 32);
#pragma unroll
      for (int t = 0; t < 4; ++t)
#pragma unroll
        for (int r = 0; r < 4; ++r) {
          const int ko = t*16 + koff + r;
          const bool dead = ((kb0 + ko) > qg) || (((wm >> ko) & 1ull) != 0ull);
          vals[t*4+r] = dead ? -3.0e12f : st[t][r];
        }
    }

    float tmax = vals[0];
#pragma unroll
    for (int i = 1; i < 16; ++i) tmax = fmaxf(tmax, vals[i]);
    tmax = fmaxf(tmax, __shfl_xor(tmax, 16));
    tmax = fmaxf(tmax, __shfl_xor(tmax, 32));
    const float m2new = fmaxf(m2, tmax * SC2);
    const float alpha = exp2f(m2 - m2new);

    float psum = 0.f;
    unsigned short* Pw = Ps[wid];
#pragma unroll
    for (int t = 0; t < 4; ++t) {
      const float p0 = exp2f(__builtin_fmaf(vals[t*4+0], SC2, -m2new));
      const float p1 = exp2f(__builtin_fmaf(vals[t*4+1], SC2, -m2new));
      const float p2 = exp2f(__builtin_fmaf(vals[t*4+2], SC2, -m2new));
      const float p3 = exp2f(__builtin_fmaf(vals[t*4+3], SC2, -m2new));
      psum += (p0 + p1) + (p2 + p3);
      const int ko = t*16 + koff;
      *(ushort4*)(Pw + q_*64 + (((ko >> 3) ^ (q_ & 7)) * 8) + (ko & 7)) =
          make_ushort4(f2bf(p0), f2bf(p1), f2bf(p2), f2bf(p3));
    }
    psum += __shfl_xor(psum, 16);
    psum += __shfl_xor(psum, 32);
    l_run = l_run * alpha + psum;
    m2 = m2new;

    // rescale O rows by alpha of that q-row
#pragma unroll
    for (int r = 0; r < 4; ++r) {
      const float ar = __shfl(alpha, koff + r);
      Oacc[0][r] *= ar; Oacc[1][r] *= ar; Oacc[2][r] *= ar; Oacc[3][r] *= ar;
    }

    // PV: O[q][d] += P[q][k] V[k][d];  A = P (rows q), B = V^T rows (cols d)
#pragma unroll
    for (int cp = 0; cp < 2; ++cp) {
      const int ko = cp*32 + hi4*8;
      bf16x8 pf = *(const bf16x8*)(Pw + q_*64 + (((ko >> 3) ^ (q_ & 7)) * 8));
#pragma unroll
      for (int n = 0; n < 4; ++n) {
        const int d = n*16 + q_;
        const int cd = ((cp*4 + hi4) ^ (d & 7)) * 8;
        bf16x8 vf = *(const bf16x8*)(Vs + d*64 + cd);
        Oacc[n] = __builtin_amdgcn_mfma_f32_16x16x32_bf16(pf, vf, Oacc[n], 0, 0, 0);
      }
    }
  }

#pragma unroll
  for (int r = 0; r < 4; ++r) {
    const float lr = __shfl(l_run, koff + r);
    const float inv = 1.f / lr;
    const int row = bi*SEQ + qbase + wid*16 + koff + r;
#pragma unroll
    for (int n = 0; n < 4; ++n)
      outb[(size_t)row*DMODEL + h*HDIM + n*16 + q_] = f2bf(Oacc[n][r] * inv);
  }
}

extern "C" void kernel_launch(void* const* d_in, const int* in_sizes, int n_in,
                              void* d_out, int out_size, void* d_ws, size_t ws_size,
                              hipStream_t stream)
{
  const float* x  = (const float*)d_in[0];
  const int*   ids= (const int*)d_in[1];
  const float* Wq = (const float*)d_in[2];
  const float* bq = (const float*)d_in[3];
  const float* Wk = (const float*)d_in[4];
  const float* bk = (const float*)d_in[5];
  const float* Wv = (const float*)d_in[6];
  const float* bv = (const float*)d_in[7];
  const float* Wo = (const float*)d_in[8];
  const float* bo = (const float*)d_in[9];
  float* out = (float*)d_out;

  char* ws = (char*)d_ws;
  unsigned short* xb   = (unsigned short*)(ws);
  unsigned short* wqb  = (unsigned short*)(ws + ( 8u<<20));
  unsigned short* wkb  = (unsigned short*)(ws + (10u<<20));
  unsigned short* wvb  = (unsigned short*)(ws + (12u<<20));
  unsigned short* wob  = (unsigned short*)(ws + (14u<<20));
  unsigned short* qbuf = (unsigned short*)(ws + (16u<<20));
  unsigned short* kbuf = (unsigned short*)(ws + (24u<<20));
  unsigned short* vbuf = (unsigned short*)(ws + (32u<<20));  // [b,h,d,s]
  unsigned short* abuf = (unsigned short*)(ws + (40u<<20));

  cast_f32_bf16<<<4096, 256, 0, stream>>>(x, xb, MROWS*DMODEL/4);
  cast_w4<<<dim3(1024, 4), 256, 0, stream>>>(Wq, Wk, Wv, Wo, wqb, wkb, wvb, wob);

  gemm_nt<0><<<dim3(24, 32), 256, 0, stream>>>(xb, wqb, wkb, wvb, bq, bk, bv,
                                               qbuf, kbuf, vbuf, nullptr);

  attn_fwd<<<dim3(SEQ/64, NHEADS, BATCH), 256, 0, stream>>>(qbuf, kbuf, vbuf, ids, abuf);

  gemm_nt<1><<<dim3(8, 32), 256, 0, stream>>>(abuf, wob, wob, wob, bo, bo, bo,
                                              nullptr, nullptr, nullptr, out);
}

// Round 3
// 136.929 us; speedup vs baseline: 2.3166x; 1.3638x over previous
//
#include <hip/hip_runtime.h>

#define DMODEL 1024
#define NHEADS 16
#define HDIM   64
#define BATCH  2
#define SEQ    2048
#define MROWS  (BATCH*SEQ)

typedef __bf16 bf16x8 __attribute__((ext_vector_type(8)));
typedef float floatx4 __attribute__((ext_vector_type(4)));

typedef const __attribute__((address_space(1))) void gvoid;
typedef __attribute__((address_space(3))) void lvoid;

__device__ inline unsigned short f2bf(float f) {
  unsigned int u = __float_as_uint(f);
  u += 0x7fffu + ((u >> 16) & 1u);
  return (unsigned short)(u >> 16);
}

__global__ void cast_f32_bf16(const float* __restrict__ in,
                              unsigned short* __restrict__ out, int n4) {
  int i = blockIdx.x * blockDim.x + threadIdx.x;
  if (i < n4) {
    float4 f = ((const float4*)in)[i];
    ((ushort4*)out)[i] = make_ushort4(f2bf(f.x), f2bf(f.y), f2bf(f.z), f2bf(f.w));
  }
}

__global__ void cast_w4(const float* __restrict__ a, const float* __restrict__ b,
                        const float* __restrict__ c, const float* __restrict__ d,
                        unsigned short* __restrict__ oa, unsigned short* __restrict__ ob,
                        unsigned short* __restrict__ oc, unsigned short* __restrict__ od) {
  const int i = blockIdx.x * blockDim.x + threadIdx.x;
  const float* s = blockIdx.y == 0 ? a : blockIdx.y == 1 ? b : blockIdx.y == 2 ? c : d;
  unsigned short* o = blockIdx.y == 0 ? oa : blockIdx.y == 1 ? ob : blockIdx.y == 2 ? oc : od;
  float4 f = ((const float4*)s)[i];
  ((ushort4*)o)[i] = make_ushort4(f2bf(f.x), f2bf(f.y), f2bf(f.z), f2bf(f.w));
}

// NT GEMM: C[m][n] = sum_k A[m][k]*W[n][k] + bias[n]
// MODE 0: fused QKV; q,k -> [b,h,s,d] bf16, v -> [b,h,d,s] bf16 (pre-transposed).
// MODE 1: fp32 row-major out (output projection).
template<int MODE>
__global__ __launch_bounds__(256)
void gemm_nt(const unsigned short* __restrict__ A,
             const unsigned short* __restrict__ W0,
             const unsigned short* __restrict__ W1,
             const unsigned short* __restrict__ W2,
             const float* __restrict__ b0,
             const float* __restrict__ b1,
             const float* __restrict__ b2,
             unsigned short* __restrict__ qout,
             unsigned short* __restrict__ kout,
             unsigned short* __restrict__ vout,
             float* __restrict__ outf)
{
  const int K = DMODEL;
  __shared__ unsigned short As[128*32];
  __shared__ unsigned short Bs[128*32];
  const int tid  = threadIdx.x;
  const int wid  = tid >> 6;
  const int lane = tid & 63;
  const int brow = blockIdx.y * 128;
  const int bcol = blockIdx.x * 128;
  const int wr = (wid >> 1) * 64;
  const int wc = (wid & 1) * 64;

  int which = 0;
  const unsigned short* Bw = W0;
  const float* bias = b0;
  int bcolL = bcol;
  if (MODE == 0) {
    which = bcol >> 10;
    Bw   = which == 0 ? W0 : which == 1 ? W1 : W2;
    bias = which == 0 ? b0 : which == 1 ? b1 : b2;
    bcolL = bcol & 1023;
  }

  floatx4 acc[4][4] = {};

  const int sr = wid*16 + (lane >> 2);
  const int sc = (lane & 3) * 8;
  const int fr = lane & 15;
  const int fk = (lane >> 4) * 8;

  for (int kt = 0; kt < K; kt += 32) {
    __syncthreads();
#pragma unroll
    for (int i = 0; i < 2; ++i) {
      __builtin_amdgcn_global_load_lds(
          (gvoid*)(A + (size_t)(brow + i*64 + sr)*K + kt + sc),
          (lvoid*)(As + i*2048 + wid*512), 16, 0, 0);
      __builtin_amdgcn_global_load_lds(
          (gvoid*)(Bw + (size_t)(bcolL + i*64 + sr)*K + kt + sc),
          (lvoid*)(Bs + i*2048 + wid*512), 16, 0, 0);
    }
    __syncthreads();
    bf16x8 af[4], bfv[4];
#pragma unroll
    for (int m = 0; m < 4; ++m)
      af[m] = *(const bf16x8*)(As + (wr + m*16 + fr)*32 + fk);
#pragma unroll
    for (int n = 0; n < 4; ++n)
      bfv[n] = *(const bf16x8*)(Bs + (wc + n*16 + fr)*32 + fk);
#pragma unroll
    for (int m = 0; m < 4; ++m)
#pragma unroll
      for (int n = 0; n < 4; ++n)
        acc[m][n] = __builtin_amdgcn_mfma_f32_16x16x32_bf16(af[m], bfv[n], acc[m][n], 0, 0, 0);
  }

  const int er = (lane >> 4) * 4;
  const int ec = lane & 15;
#pragma unroll
  for (int m = 0; m < 4; ++m) {
#pragma unroll
    for (int n = 0; n < 4; ++n) {
      const int colL = bcolL + wc + n*16 + ec;
      const float bv = bias[colL];
#pragma unroll
      for (int j = 0; j < 4; ++j) {
        const int row = brow + wr + m*16 + er + j;
        const float val = acc[m][n][j] + bv;
        if (MODE == 0) {
          const int bi = row >> 11, s = row & 2047;
          const int hh = colL >> 6, dd = colL & 63;
          if (which == 2)
            vout[((size_t)(bi*NHEADS + hh)*HDIM + dd)*SEQ + s] = f2bf(val);
          else {
            unsigned short* o = (which == 0) ? qout : kout;
            o[((size_t)(bi*NHEADS + hh)*SEQ + s)*HDIM + dd] = f2bf(val);
          }
        } else {
          outf[(size_t)row*DMODEL + bcol + wc + n*16 + ec] = val;
        }
      }
    }
  }
}

// Flash attention. grid (hb=32, y=32), 256 thr = 4 waves, wave owns 16 q-rows,
// KVBLK=64. qt derived from y so each CU's 4 resident blocks (ids +256 apart)
// have equal total work. Double-buffered K/V staging via global_load_lds with
// counted vmcnt(4) + raw s_barrier (loads stay in flight across barriers).
// Pad mask via per-step ballot. Swapped QK^T, exp2-domain online softmax.
__global__ __launch_bounds__(256, 4)
void attn_fwd(const unsigned short* __restrict__ qb,
              const unsigned short* __restrict__ kb,
              const unsigned short* __restrict__ vtb,
              const int* __restrict__ ids,
              unsigned short* __restrict__ outb)
{
  const int hb = blockIdx.x;
  const int h = hb & 15, bi = hb >> 4;
  const int y = blockIdx.y;
  const int jm = y >> 3, mm = y & 7;
  const int qt = jm*8 + ((jm & 1) ? 7 - mm : mm);   // per-CU balanced work map

  const int tid = threadIdx.x, wid = tid >> 6, lane = tid & 63;
  const int qbase = qt * 64;
  const size_t hoff = (size_t)(bi*NHEADS + h) * SEQ * HDIM;
  const unsigned short* Qh  = qb  + hoff;
  const unsigned short* Kh  = kb  + hoff;
  const unsigned short* Vth = vtb + hoff;   // [d][s]

  __shared__ unsigned short Ks[2][64*64];   // [k][d], chunk-swizzled
  __shared__ unsigned short Vs[2][64*64];   // [d][k], chunk-swizzled
  __shared__ unsigned short Ps[4][16*64];   // per-wave P, chunk-swizzled

  const int q_   = lane & 15;
  const int hi4  = lane >> 4;
  const int koff = hi4 * 4;
  const int qg = qbase + wid*16 + q_;
  bf16x8 qf[2];
#pragma unroll
  for (int c = 0; c < 2; ++c)
    qf[c] = *(const bf16x8*)(Qh + (size_t)qg*HDIM + c*32 + hi4*8);

  const float SC2 = 0.125f * 1.44269504088896f;
  float m2 = -INFINITY, l_run = 0.f;
  floatx4 Oacc[4] = {};

  // staging geometry: 512 chunks of 16B; thread covers chunks tid and tid+256
  const int r0 = tid >> 3;
  const int sw = ((tid & 7) ^ (r0 & 7)) * 8;   // (r0+32)&7 == r0&7

#define STAGE(T, B) do {                                                     \
    const unsigned short* kbase_ = Kh + (size_t)((T)*64) * HDIM;             \
    const unsigned short* vbase_ = Vth + (T)*64;                             \
    __builtin_amdgcn_global_load_lds((gvoid*)(kbase_ + r0*64 + sw),          \
                                     (lvoid*)(Ks[B] + tid*8), 16, 0, 0);     \
    __builtin_amdgcn_global_load_lds((gvoid*)(kbase_ + (r0+32)*64 + sw),     \
                                     (lvoid*)(Ks[B] + (tid+256)*8), 16, 0, 0);\
    __builtin_amdgcn_global_load_lds((gvoid*)(vbase_ + (size_t)r0*SEQ + sw), \
                                     (lvoid*)(Vs[B] + tid*8), 16, 0, 0);     \
    __builtin_amdgcn_global_load_lds((gvoid*)(vbase_ + (size_t)(r0+32)*SEQ + sw),\
                                     (lvoid*)(Vs[B] + (tid+256)*8), 16, 0, 0);\
  } while (0)

  const int nT = qt + 1;
  STAGE(0, 0);

  for (int kbv = 0; kbv < nT; ++kbv) {
    const int kb0 = kbv * 64;
    const int bufc = kbv & 1;
    const int pv = ids[bi*SEQ + kb0 + lane];
    if (kbv + 1 < nT) {
      STAGE(kbv + 1, bufc ^ 1);
      asm volatile("s_waitcnt vmcnt(4)" ::: "memory");
    } else {
      asm volatile("s_waitcnt vmcnt(0)" ::: "memory");
    }
    const unsigned long long wm = __ballot(pv == 0);
    __builtin_amdgcn_s_barrier();
    __builtin_amdgcn_sched_barrier(0);

    // QK^T (swapped): st[t] rows = keys t*16+koff+r, col = q_
    floatx4 st[4] = {};
#pragma unroll
    for (int t = 0; t < 4; ++t) {
      const int kr = t*16 + q_;
#pragma unroll
      for (int c = 0; c < 2; ++c) {
        const int cd = ((c*4 + hi4) ^ (kr & 7)) * 8;
        bf16x8 kf = *(const bf16x8*)(Ks[bufc] + kr*64 + cd);
        st[t] = __builtin_amdgcn_mfma_f32_16x16x32_bf16(kf, qf[c], st[t], 0, 0, 0);
      }
    }

    float vals[16];
    if ((wm == 0ull) && (kbv != qt)) {
#pragma unroll
      for (int t = 0; t < 4; ++t)
#pragma unroll
        for (int r = 0; r < 4; ++r) vals[t*4+r] = st[t][r];
    } else {
#pragma unroll
      for (int t = 0; t < 4; ++t)
#pragma unroll
        for (int r = 0; r < 4; ++r) {
          const int ko = t*16 + koff + r;
          const bool dead = ((kb0 + ko) > qg) || (((wm >> ko) & 1ull) != 0ull);
          vals[t*4+r] = dead ? -3.0e12f : st[t][r];
        }
    }

    float tmax = vals[0];
#pragma unroll
    for (int i = 1; i < 16; ++i) tmax = fmaxf(tmax, vals[i]);
    tmax = fmaxf(tmax, __shfl_xor(tmax, 16));
    tmax = fmaxf(tmax, __shfl_xor(tmax, 32));
    const float m2new = fmaxf(m2, tmax * SC2);
    const float alpha = exp2f(m2 - m2new);

    float psum = 0.f;
    unsigned short* Pw = Ps[wid];
#pragma unroll
    for (int t = 0; t < 4; ++t) {
      const float p0 = exp2f(__builtin_fmaf(vals[t*4+0], SC2, -m2new));
      const float p1 = exp2f(__builtin_fmaf(vals[t*4+1], SC2, -m2new));
      const float p2 = exp2f(__builtin_fmaf(vals[t*4+2], SC2, -m2new));
      const float p3 = exp2f(__builtin_fmaf(vals[t*4+3], SC2, -m2new));
      psum += (p0 + p1) + (p2 + p3);
      const int ko = t*16 + koff;
      *(ushort4*)(Pw + q_*64 + (((ko >> 3) ^ (q_ & 7)) * 8) + (ko & 7)) =
          make_ushort4(f2bf(p0), f2bf(p1), f2bf(p2), f2bf(p3));
    }
    psum += __shfl_xor(psum, 16);
    psum += __shfl_xor(psum, 32);
    l_run = l_run * alpha + psum;
    m2 = m2new;

#pragma unroll
    for (int r = 0; r < 4; ++r) {
      const float ar = __shfl(alpha, koff + r);
      Oacc[0][r] *= ar; Oacc[1][r] *= ar; Oacc[2][r] *= ar; Oacc[3][r] *= ar;
    }

    // PV: A = P rows (q), B = V^T rows (d)
#pragma unroll
    for (int cp = 0; cp < 2; ++cp) {
      const int ko = cp*32 + hi4*8;
      bf16x8 pf = *(const bf16x8*)(Pw + q_*64 + (((ko >> 3) ^ (q_ & 7)) * 8));
#pragma unroll
      for (int n = 0; n < 4; ++n) {
        const int d = n*16 + q_;
        const int cd = ((cp*4 + hi4) ^ (d & 7)) * 8;
        bf16x8 vf = *(const bf16x8*)(Vs[bufc] + d*64 + cd);
        Oacc[n] = __builtin_amdgcn_mfma_f32_16x16x32_bf16(pf, vf, Oacc[n], 0, 0, 0);
      }
    }
    __builtin_amdgcn_s_barrier();
  }
#undef STAGE

#pragma unroll
  for (int r = 0; r < 4; ++r) {
    const float lr = __shfl(l_run, koff + r);
    const float inv = 1.f / lr;
    const int row = bi*SEQ + qbase + wid*16 + koff + r;
#pragma unroll
    for (int n = 0; n < 4; ++n)
      outb[(size_t)row*DMODEL + h*HDIM + n*16 + q_] = f2bf(Oacc[n][r] * inv);
  }
}

extern "C" void kernel_launch(void* const* d_in, const int* in_sizes, int n_in,
                              void* d_out, int out_size, void* d_ws, size_t ws_size,
                              hipStream_t stream)
{
  const float* x  = (const float*)d_in[0];
  const int*   ids= (const int*)d_in[1];
  const float* Wq = (const float*)d_in[2];
  const float* bq = (const float*)d_in[3];
  const float* Wk = (const float*)d_in[4];
  const float* bk = (const float*)d_in[5];
  const float* Wv = (const float*)d_in[6];
  const float* bv = (const float*)d_in[7];
  const float* Wo = (const float*)d_in[8];
  const float* bo = (const float*)d_in[9];
  float* out = (float*)d_out;

  char* ws = (char*)d_ws;
  unsigned short* xb   = (unsigned short*)(ws);
  unsigned short* wqb  = (unsigned short*)(ws + ( 8u<<20));
  unsigned short* wkb  = (unsigned short*)(ws + (10u<<20));
  unsigned short* wvb  = (unsigned short*)(ws + (12u<<20));
  unsigned short* wob  = (unsigned short*)(ws + (14u<<20));
  unsigned short* qbuf = (unsigned short*)(ws + (16u<<20));
  unsigned short* kbuf = (unsigned short*)(ws + (24u<<20));
  unsigned short* vbuf = (unsigned short*)(ws + (32u<<20));  // [b,h,d,s]
  unsigned short* abuf = (unsigned short*)(ws + (40u<<20));

  cast_f32_bf16<<<4096, 256, 0, stream>>>(x, xb, MROWS*DMODEL/4);
  cast_w4<<<dim3(1024, 4), 256, 0, stream>>>(Wq, Wk, Wv, Wo, wqb, wkb, wvb, wob);

  gemm_nt<0><<<dim3(24, 32), 256, 0, stream>>>(xb, wqb, wkb, wvb, bq, bk, bv,
                                               qbuf, kbuf, vbuf, nullptr);

  attn_fwd<<<dim3(32, 32), 256, 0, stream>>>(qbuf, kbuf, vbuf, ids, abuf);

  gemm_nt<1><<<dim3(8, 32), 256, 0, stream>>>(abuf, wob, wob, wob, bo, bo, bo,
                                              nullptr, nullptr, nullptr, out);
}

// Round 4
// 127.164 us; speedup vs baseline: 2.4945x; 1.0768x over previous
//
#include <hip/hip_runtime.h>

#define DMODEL 1024
#define NHEADS 16
#define HDIM   64
#define BATCH  2
#define SEQ    2048
#define MROWS  (BATCH*SEQ)

typedef __bf16 bf16x8 __attribute__((ext_vector_type(8)));
typedef float floatx4 __attribute__((ext_vector_type(4)));

typedef const __attribute__((address_space(1))) void gvoid;
typedef __attribute__((address_space(3))) void lvoid;

__device__ inline unsigned short f2bf(float f) {
  unsigned int u = __float_as_uint(f);
  u += 0x7fffu + ((u >> 16) & 1u);
  return (unsigned short)(u >> 16);
}

__global__ void cast_f32_bf16(const float* __restrict__ in,
                              unsigned short* __restrict__ out, int n4) {
  int i = blockIdx.x * blockDim.x + threadIdx.x;
  if (i < n4) {
    float4 f = ((const float4*)in)[i];
    ((ushort4*)out)[i] = make_ushort4(f2bf(f.x), f2bf(f.y), f2bf(f.z), f2bf(f.w));
  }
}

__global__ void cast_w4(const float* __restrict__ a, const float* __restrict__ b,
                        const float* __restrict__ c, const float* __restrict__ d,
                        unsigned short* __restrict__ oa, unsigned short* __restrict__ ob,
                        unsigned short* __restrict__ oc, unsigned short* __restrict__ od) {
  const int i = blockIdx.x * blockDim.x + threadIdx.x;
  const float* s = blockIdx.y == 0 ? a : blockIdx.y == 1 ? b : blockIdx.y == 2 ? c : d;
  unsigned short* o = blockIdx.y == 0 ? oa : blockIdx.y == 1 ? ob : blockIdx.y == 2 ? oc : od;
  float4 f = ((const float4*)s)[i];
  ((ushort4*)o)[i] = make_ushort4(f2bf(f.x), f2bf(f.y), f2bf(f.z), f2bf(f.w));
}

// NT GEMM: C[m][n] = sum_k A[m][k]*W[n][k] + bias[n]
// MODE 0: fused QKV; q,k -> [b,h,s,d] bf16, v -> [b,h,d,s] bf16 (pre-transposed).
// MODE 1: fp32 row-major out (output projection).
template<int MODE>
__global__ __launch_bounds__(256)
void gemm_nt(const unsigned short* __restrict__ A,
             const unsigned short* __restrict__ W0,
             const unsigned short* __restrict__ W1,
             const unsigned short* __restrict__ W2,
             const float* __restrict__ b0,
             const float* __restrict__ b1,
             const float* __restrict__ b2,
             unsigned short* __restrict__ qout,
             unsigned short* __restrict__ kout,
             unsigned short* __restrict__ vout,
             float* __restrict__ outf)
{
  const int K = DMODEL;
  __shared__ unsigned short As[128*32];
  __shared__ unsigned short Bs[128*32];
  const int tid  = threadIdx.x;
  const int wid  = tid >> 6;
  const int lane = tid & 63;
  const int brow = blockIdx.y * 128;
  const int bcol = blockIdx.x * 128;
  const int wr = (wid >> 1) * 64;
  const int wc = (wid & 1) * 64;

  int which = 0;
  const unsigned short* Bw = W0;
  const float* bias = b0;
  int bcolL = bcol;
  if (MODE == 0) {
    which = bcol >> 10;
    Bw   = which == 0 ? W0 : which == 1 ? W1 : W2;
    bias = which == 0 ? b0 : which == 1 ? b1 : b2;
    bcolL = bcol & 1023;
  }

  floatx4 acc[4][4] = {};

  const int sr = wid*16 + (lane >> 2);
  const int sc = (lane & 3) * 8;
  const int fr = lane & 15;
  const int fk = (lane >> 4) * 8;

  for (int kt = 0; kt < K; kt += 32) {
    __syncthreads();
#pragma unroll
    for (int i = 0; i < 2; ++i) {
      __builtin_amdgcn_global_load_lds(
          (gvoid*)(A + (size_t)(brow + i*64 + sr)*K + kt + sc),
          (lvoid*)(As + i*2048 + wid*512), 16, 0, 0);
      __builtin_amdgcn_global_load_lds(
          (gvoid*)(Bw + (size_t)(bcolL + i*64 + sr)*K + kt + sc),
          (lvoid*)(Bs + i*2048 + wid*512), 16, 0, 0);
    }
    __syncthreads();
    bf16x8 af[4], bfv[4];
#pragma unroll
    for (int m = 0; m < 4; ++m)
      af[m] = *(const bf16x8*)(As + (wr + m*16 + fr)*32 + fk);
#pragma unroll
    for (int n = 0; n < 4; ++n)
      bfv[n] = *(const bf16x8*)(Bs + (wc + n*16 + fr)*32 + fk);
#pragma unroll
    for (int m = 0; m < 4; ++m)
#pragma unroll
      for (int n = 0; n < 4; ++n)
        acc[m][n] = __builtin_amdgcn_mfma_f32_16x16x32_bf16(af[m], bfv[n], acc[m][n], 0, 0, 0);
  }

  const int er = (lane >> 4) * 4;
  const int ec = lane & 15;
#pragma unroll
  for (int m = 0; m < 4; ++m) {
#pragma unroll
    for (int n = 0; n < 4; ++n) {
      const int colL = bcolL + wc + n*16 + ec;
      const float bv = bias[colL];
#pragma unroll
      for (int j = 0; j < 4; ++j) {
        const int row = brow + wr + m*16 + er + j;
        const float val = acc[m][n][j] + bv;
        if (MODE == 0) {
          const int bi = row >> 11, s = row & 2047;
          const int hh = colL >> 6, dd = colL & 63;
          if (which == 2)
            vout[((size_t)(bi*NHEADS + hh)*HDIM + dd)*SEQ + s] = f2bf(val);
          else {
            unsigned short* o = (which == 0) ? qout : kout;
            o[((size_t)(bi*NHEADS + hh)*SEQ + s)*HDIM + dd] = f2bf(val);
          }
        } else {
          outf[(size_t)row*DMODEL + bcol + wc + n*16 + ec] = val;
        }
      }
    }
  }
}

// Flash attention. grid (hb=32, pair=16), 256 thr = 4 waves. Each block runs
// q-tiles (pr, 31-pr) sequentially -> every block exactly 17 steps (flat
// occupancy, no tail). KVBLK=128, QBLK=64. Double-buffered K/V via
// global_load_lds with pre-swizzled source + counted vmcnt(8). Swapped QK^T,
// exp2-domain online softmax with defer-max (THR=8), pad mask via ballot.
__global__ __launch_bounds__(256, 2)
void attn_fwd(const unsigned short* __restrict__ qb,
              const unsigned short* __restrict__ kb,
              const unsigned short* __restrict__ vtb,
              const int* __restrict__ ids,
              unsigned short* __restrict__ outb)
{
  const int hb = blockIdx.x;
  const int pr = blockIdx.y;
  const int h = hb & 15, bi = hb >> 4;

  const int tid = threadIdx.x, wid = tid >> 6, lane = tid & 63;
  const size_t hoff = (size_t)(bi*NHEADS + h) * SEQ * HDIM;
  const unsigned short* Qh  = qb  + hoff;
  const unsigned short* Kh  = kb  + hoff;
  const unsigned short* Vth = vtb + hoff;   // [d][s]

  __shared__ unsigned short Ks[2][128*64];  // [k][d] chunk-swizzled (16KB each)
  __shared__ unsigned short Vs[2][64*128];  // [d][k] chunk-swizzled (16KB each)
  __shared__ unsigned short Ps[4][16*128];  // per-wave P (4KB each)

  const int q_   = lane & 15;
  const int hi4  = lane >> 4;
  const int koff = hi4 * 4;
  const float SC2 = 0.125f * 1.44269504088896f;

  // staging geometry: K tile = 1024 chunks of 16B, V tile = 1024 chunks
  const int krow0 = tid >> 3;                       // +i*32
  const int ksw   = ((tid & 7) ^ ((tid >> 3) & 7)) * 8;
  const int vrow0 = tid >> 4;                       // +i*16
  const int vsw   = ((tid & 15) ^ ((tid >> 4) & 7)) * 8;

#define STAGE(T, B) do {                                                       \
    const unsigned short* kbase_ = Kh + (size_t)(T)*128*HDIM;                  \
    const unsigned short* vbase_ = Vth + (size_t)(T)*128;                      \
    _Pragma("unroll")                                                          \
    for (int i_ = 0; i_ < 4; ++i_)                                             \
      __builtin_amdgcn_global_load_lds(                                        \
          (gvoid*)(kbase_ + (size_t)(krow0 + i_*32)*HDIM + ksw),               \
          (lvoid*)(Ks[B] + (tid + i_*256)*8), 16, 0, 0);                       \
    _Pragma("unroll")                                                          \
    for (int i_ = 0; i_ < 4; ++i_)                                             \
      __builtin_amdgcn_global_load_lds(                                        \
          (gvoid*)(vbase_ + (size_t)(vrow0 + i_*16)*SEQ + vsw),                \
          (lvoid*)(Vs[B] + (tid + i_*256)*8), 16, 0, 0);                       \
  } while (0)

  for (int half = 0; half < 2; ++half) {
    const int qt = half ? 31 - pr : pr;
    const int qbase = qt * 64;
    const int qg = qbase + wid*16 + q_;
    bf16x8 qf[2];
#pragma unroll
    for (int c = 0; c < 2; ++c)
      qf[c] = *(const bf16x8*)(Qh + (size_t)qg*HDIM + c*32 + hi4*8);

    float m2 = -INFINITY, l_run = 0.f;
    floatx4 Oacc[4] = {};

    const int nT = (qt >> 1) + 1;
    STAGE(0, 0);

    for (int kbv = 0; kbv < nT; ++kbv) {
      const int kb0 = kbv * 128;
      const int bufc = kbv & 1;
      const int pv0 = ids[bi*SEQ + kb0 + lane];
      const int pv1 = ids[bi*SEQ + kb0 + 64 + lane];
      if (kbv + 1 < nT) {
        STAGE(kbv + 1, bufc ^ 1);
        asm volatile("s_waitcnt vmcnt(8)" ::: "memory");
      } else {
        asm volatile("s_waitcnt vmcnt(0)" ::: "memory");
      }
      const unsigned long long wma = __ballot(pv0 == 0);
      const unsigned long long wmb = __ballot(pv1 == 0);
      __builtin_amdgcn_s_barrier();
      __builtin_amdgcn_sched_barrier(0);

      // QK^T (swapped): st[t] rows = keys t*16+koff+r, col = q_
      floatx4 st[8];
#pragma unroll
      for (int t = 0; t < 8; ++t) {
        st[t] = (floatx4){0.f, 0.f, 0.f, 0.f};
        const int kr = t*16 + q_;
#pragma unroll
        for (int c = 0; c < 2; ++c) {
          const int cd = ((c*4 + hi4) ^ (kr & 7)) * 8;
          bf16x8 kf = *(const bf16x8*)(Ks[bufc] + kr*64 + cd);
          st[t] = __builtin_amdgcn_mfma_f32_16x16x32_bf16(kf, qf[c], st[t], 0, 0, 0);
        }
      }

      float vals[32];
      if (((wma | wmb) == 0ull) && (kbv + 1 < nT)) {
#pragma unroll
        for (int t = 0; t < 8; ++t)
#pragma unroll
          for (int r = 0; r < 4; ++r) vals[t*4+r] = st[t][r];
      } else {
#pragma unroll
        for (int t = 0; t < 8; ++t)
#pragma unroll
          for (int r = 0; r < 4; ++r) {
            const int ko = t*16 + koff + r;
            const unsigned long long wm = (t < 4) ? wma : wmb;
            const bool dead = ((kb0 + ko) > qg) || (((wm >> (ko & 63)) & 1ull) != 0ull);
            vals[t*4+r] = dead ? -3.0e12f : st[t][r];
          }
      }

      // tree max (max3-friendly)
      float g[8];
#pragma unroll
      for (int t = 0; t < 8; ++t)
        g[t] = fmaxf(fmaxf(vals[t*4], vals[t*4+1]), fmaxf(vals[t*4+2], vals[t*4+3]));
      float tmax = fmaxf(fmaxf(fmaxf(g[0], g[1]), fmaxf(g[2], g[3])),
                         fmaxf(fmaxf(g[4], g[5]), fmaxf(g[6], g[7])));
      tmax = fmaxf(tmax, __shfl_xor(tmax, 16));
      tmax = fmaxf(tmax, __shfl_xor(tmax, 32));
      const float m2cand = tmax * SC2;

      // defer-max: skip rescale when no row's max grew past THR=8 (log2)
      if (!__all(m2cand <= m2 + 8.f)) {
        const float m2new = fmaxf(m2, m2cand);
        const float alpha = exp2f(m2 - m2new);
        l_run *= alpha;
#pragma unroll
        for (int r = 0; r < 4; ++r) {
          const float ar = __shfl(alpha, koff + r);
          Oacc[0][r] *= ar; Oacc[1][r] *= ar; Oacc[2][r] *= ar; Oacc[3][r] *= ar;
        }
        m2 = m2new;
      }

      float psum = 0.f;
      unsigned short* Pw = Ps[wid];
#pragma unroll
      for (int t = 0; t < 8; ++t) {
        const float p0 = exp2f(__builtin_fmaf(vals[t*4+0], SC2, -m2));
        const float p1 = exp2f(__builtin_fmaf(vals[t*4+1], SC2, -m2));
        const float p2 = exp2f(__builtin_fmaf(vals[t*4+2], SC2, -m2));
        const float p3 = exp2f(__builtin_fmaf(vals[t*4+3], SC2, -m2));
        psum += (p0 + p1) + (p2 + p3);
        const int cl = t*2 + (hi4 >> 1);
        *(ushort4*)(Pw + q_*128 + ((cl ^ (q_ & 7)) * 8) + ((hi4 & 1) * 4)) =
            make_ushort4(f2bf(p0), f2bf(p1), f2bf(p2), f2bf(p3));
      }
      psum += __shfl_xor(psum, 16);
      psum += __shfl_xor(psum, 32);
      l_run += psum;

      // PV: A = P rows (q), B = V^T rows (d); 4 k-chunks of 32
#pragma unroll
      for (int ks = 0; ks < 4; ++ks) {
        const int cl = ks*4 + hi4;
        bf16x8 pf = *(const bf16x8*)(Pw + q_*128 + ((cl ^ (q_ & 7)) * 8));
#pragma unroll
        for (int n = 0; n < 4; ++n) {
          const int d = n*16 + q_;
          bf16x8 vf = *(const bf16x8*)(Vs[bufc] + d*128 + ((cl ^ (d & 7)) * 8));
          Oacc[n] = __builtin_amdgcn_mfma_f32_16x16x32_bf16(pf, vf, Oacc[n], 0, 0, 0);
        }
      }
      __builtin_amdgcn_s_barrier();
    }

#pragma unroll
    for (int r = 0; r < 4; ++r) {
      const float lr = __shfl(l_run, koff + r);
      const float inv = 1.f / lr;
      const int row = bi*SEQ + qbase + wid*16 + koff + r;
#pragma unroll
      for (int n = 0; n < 4; ++n)
        outb[(size_t)row*DMODEL + h*HDIM + n*16 + q_] = f2bf(Oacc[n][r] * inv);
    }
  }
#undef STAGE
}

extern "C" void kernel_launch(void* const* d_in, const int* in_sizes, int n_in,
                              void* d_out, int out_size, void* d_ws, size_t ws_size,
                              hipStream_t stream)
{
  const float* x  = (const float*)d_in[0];
  const int*   ids= (const int*)d_in[1];
  const float* Wq = (const float*)d_in[2];
  const float* bq = (const float*)d_in[3];
  const float* Wk = (const float*)d_in[4];
  const float* bk = (const float*)d_in[5];
  const float* Wv = (const float*)d_in[6];
  const float* bv = (const float*)d_in[7];
  const float* Wo = (const float*)d_in[8];
  const float* bo = (const float*)d_in[9];
  float* out = (float*)d_out;

  char* ws = (char*)d_ws;
  unsigned short* xb   = (unsigned short*)(ws);
  unsigned short* wqb  = (unsigned short*)(ws + ( 8u<<20));
  unsigned short* wkb  = (unsigned short*)(ws + (10u<<20));
  unsigned short* wvb  = (unsigned short*)(ws + (12u<<20));
  unsigned short* wob  = (unsigned short*)(ws + (14u<<20));
  unsigned short* qbuf = (unsigned short*)(ws + (16u<<20));
  unsigned short* kbuf = (unsigned short*)(ws + (24u<<20));
  unsigned short* vbuf = (unsigned short*)(ws + (32u<<20));  // [b,h,d,s]
  unsigned short* abuf = (unsigned short*)(ws + (40u<<20));

  cast_f32_bf16<<<4096, 256, 0, stream>>>(x, xb, MROWS*DMODEL/4);
  cast_w4<<<dim3(1024, 4), 256, 0, stream>>>(Wq, Wk, Wv, Wo, wqb, wkb, wvb, wob);

  gemm_nt<0><<<dim3(24, 32), 256, 0, stream>>>(xb, wqb, wkb, wvb, bq, bk, bv,
                                               qbuf, kbuf, vbuf, nullptr);

  attn_fwd<<<dim3(32, 16), 256, 0, stream>>>(qbuf, kbuf, vbuf, ids, abuf);

  gemm_nt<1><<<dim3(8, 32), 256, 0, stream>>>(abuf, wob, wob, wob, bo, bo, bo,
                                              nullptr, nullptr, nullptr, out);
}